// Round 9
// baseline (3554.807 us; speedup 1.0000x reference)
//
#include <hip/hip_runtime.h>
#include <cstdint>
#include <cstddef>

#define BATCH 256
#define SEQ   512
#define HID   512
#define VOCAB 128

#define BT     16              // batch rows per block tile
#define HSTRB  272             // LDS half-row stride in BYTES (256 + 16, 16B-aligned)
#define LOG2E2 2.88539008177793f   // 2*log2(e): e^{2z} = 2^(z*LOG2E2), baked into E and fq

typedef __attribute__((ext_vector_type(4))) int   i32x4;
typedef __attribute__((ext_vector_type(4))) float f32x4;

// ---- abs-max reduction (for quantization scales) ----
__global__ void maxred_kernel(const float* __restrict__ src, int n,
                              unsigned int* __restrict__ dst) {
  float m = 0.f;
  for (int i = blockIdx.x * blockDim.x + threadIdx.x; i < n; i += gridDim.x * blockDim.x)
    m = fmaxf(m, fabsf(src[i]));
#pragma unroll
  for (int off = 32; off; off >>= 1)
    m = fmaxf(m, __shfl_down(m, off));
  if ((threadIdx.x & 63) == 0) atomicMax(dst, __float_as_uint(m));
}

// E'[v][j] = (sum_k emb[v][k]*W_ih[k][j] + b_ih[j] + b_hh[j]) * 2*log2(e)
__global__ __launch_bounds__(512) void eproj_kernel(const float* __restrict__ emb,
                                                    const float* __restrict__ W_ih,
                                                    const float* __restrict__ b_ih,
                                                    const float* __restrict__ b_hh,
                                                    float* __restrict__ E) {
  __shared__ float es[8][64];
  const int j = threadIdx.x;
  const int v0 = blockIdx.x * 8;
  float acc[8];
#pragma unroll
  for (int v = 0; v < 8; ++v) acc[v] = 0.f;
  for (int k0 = 0; k0 < HID; k0 += 64) {
    __syncthreads();
    es[j >> 6][j & 63] = emb[(size_t)(v0 + (j >> 6)) * HID + k0 + (j & 63)];
    __syncthreads();
#pragma unroll 8
    for (int kk = 0; kk < 64; ++kk) {
      const float w = W_ih[(size_t)(k0 + kk) * HID + j];
#pragma unroll
      for (int v = 0; v < 8; ++v) acc[v] += es[v][kk] * w;
    }
  }
  const float bias = b_ih[j] + b_hh[j];
#pragma unroll
  for (int v = 0; v < 8; ++v)
    E[(size_t)(v0 + v) * HID + j] = (acc[v] + bias) * LOG2E2;
}

// Pack [W_hh | W_ho] (512 x 640) into i8 MFMA B-fragments for 16x16x64.
// Fragment f = nt*8+kt8: lane l holds 16 i8 = B[k = kt8*64 + (l>>4)*16 + i][n = nt*16 + (l&15)]
__global__ void pack8_kernel(const float* __restrict__ W_hh,
                             const float* __restrict__ W_ho,
                             const float* __restrict__ sc,   // sc[0]=max|W_hh|, sc[1]=max|W_ho|
                             uint4* __restrict__ Wf8) {
  const int f = blockIdx.x;            // 0..319 (40 nt * 8 kt8)
  const int nt = f >> 3, kt8 = f & 7;
  const int lane = threadIdx.x;
  const int q = lane >> 4, nn = lane & 15;
  const int n = nt * 16 + nn;
  const float inv = 127.f / ((nt < 32) ? sc[0] : sc[1]);
  union { int8_t b[16]; uint4 u; } val;
#pragma unroll
  for (int i = 0; i < 16; ++i) {
    const int k = kt8 * 64 + q * 16 + i;
    const float w = (n < HID) ? W_hh[(size_t)k * HID + n]
                              : W_ho[(size_t)k * VOCAB + (n - HID)];
    val.b[i] = (int8_t)__float2int_rn(w * inv);
  }
  Wf8[(size_t)f * 64 + lane] = val.u;
}

// Recurrence with 2-WAY HIDDEN SPLIT: 32 blocks = 16 batch-tiles x 2 hidden-halves.
// Block (tile,half) computes h_t[cols half*256..+256) for its 16 batch rows.
// Own k-half of h_{t-1} comes from LDS (as before); PARTNER k-half is read directly
// from Hall (global), which the partner publishes each step via release-flag.
// Spin is placed AFTER issuing the own-k MFMAs so flag latency overlaps the MFMA
// pipe. 512 steps x per-step handshake through L3 (agent-scope atomics).
// All 32 blocks are co-resident (<=256 CUs) so the spin cannot deadlock.
__global__ __launch_bounds__(512, 2)
void rnn_kernel(const int* __restrict__ x,
                const float* __restrict__ E,
                const uint4* __restrict__ Wf8,
                const float* __restrict__ sc,
                int8_t* __restrict__ Hall,
                float* __restrict__ outH,
                unsigned int* __restrict__ flags) {
  __shared__ __align__(16) int8_t hbuf[2][BT][HSTRB];   // own half only: 8.5 KB dbuf

  const int tid = threadIdx.x;
  const int wave = tid >> 6, lane = tid & 63;
  const int q = lane >> 4, nn = lane & 15;
  const int bid = blockIdx.x;
  const int tile = bid & 15, half = bid >> 4;           // partner = bid ^ 16 (same XCD mod 8)
  const int r0 = tile * BT;
  const int colbase = half * 256 + wave * 32;           // + j*16 + nn  (own output cols)
  const int kho = half * 4;                             // own kt range (global kt index)
  const int khp = 4 - kho;                              // partner kt range
  unsigned int* const myflag = flags + tile * 2 + half;
  unsigned int* const pflag  = flags + tile * 2 + (1 - half);
  const float fq = sc[0] * (LOG2E2 / (127.f * 127.f));

  // 2 weight strips per wave: nt = half*16 + wave*2 + j, pinned in AGPRs (64 regs)
  i32x4 wa[2][8];
  {
    const uint4* wb = Wf8 + lane;
#pragma unroll
    for (int j = 0; j < 2; ++j)
#pragma unroll
      for (int kt = 0; kt < 8; ++kt)
        wa[j][kt] = __builtin_bit_cast(i32x4,
            wb[(size_t)((half * 16 + wave * 2 + j) * 8 + kt) * 64]);
  }
#pragma unroll
  for (int j = 0; j < 2; ++j)
#pragma unroll
    for (int kt = 0; kt < 8; ++kt)
      asm volatile("" : "+a"(wa[j][kt]));

  // token prefetch for t=0
  int tokc[4];
#pragma unroll
  for (int r = 0; r < 4; ++r) tokc[r] = x[(size_t)(r0 + q * 4 + r) * SEQ + 0];

  int cur = 0;
  for (int t = 0; t < SEQ; ++t) {
    int tokn[4];
    const int tn = (t + 1 < SEQ) ? t + 1 : t;
#pragma unroll
    for (int r = 0; r < 4; ++r) tokn[r] = x[(size_t)(r0 + q * 4 + r) * SEQ + tn];

    // E' rows, own cols only (8 scalars); K-loop hides the gather latency
    float ev[2][4];
#pragma unroll
    for (int j = 0; j < 2; ++j)
#pragma unroll
      for (int r = 0; r < 4; ++r)
        ev[j][r] = E[(size_t)tokc[r] * HID + colbase + j * 16 + nn];

    i32x4 acc[2];
    acc[0] = i32x4{0, 0, 0, 0};
    acc[1] = i32x4{0, 0, 0, 0};

    if (t > 0) {
      // (1) own k-half from LDS — issue first, occupies the MFMA pipe ~320 cy
#pragma unroll
      for (int ktl = 0; ktl < 4; ++ktl) {
        const i32x4 a = *(const i32x4*)&hbuf[cur][nn][ktl * 64 + q * 16];
        acc[0] = __builtin_amdgcn_mfma_i32_16x16x64_i8(a, wa[0][kho + ktl], acc[0], 0, 0, 0);
        acc[1] = __builtin_amdgcn_mfma_i32_16x16x64_i8(a, wa[1][kho + ktl], acc[1], 0, 0, 0);
      }
      // (2) spin for partner h_{t-1} (flag >= t); overlaps MFMA pipe drain.
      //     Uniform branch: all lanes load the same address (coalesces to one request).
      while (__hip_atomic_load(pflag, __ATOMIC_ACQUIRE, __HIP_MEMORY_SCOPE_AGENT)
             < (unsigned)t)
        __builtin_amdgcn_s_sleep(1);
      // (3) partner k-half directly from Hall (16B/lane, L3-fresh after acquire-inv)
      const int8_t* hp = Hall + ((size_t)(r0 + nn) * SEQ + (t - 1)) * HID + (256 - half * 256);
      i32x4 pa[4];
#pragma unroll
      for (int ktl = 0; ktl < 4; ++ktl)
        pa[ktl] = *(const i32x4*)(hp + ktl * 64 + q * 16);
#pragma unroll
      for (int ktl = 0; ktl < 4; ++ktl) {
        acc[0] = __builtin_amdgcn_mfma_i32_16x16x64_i8(pa[ktl], wa[0][khp + ktl], acc[0], 0, 0, 0);
        acc[1] = __builtin_amdgcn_mfma_i32_16x16x64_i8(pa[ktl], wa[1][khp + ktl], acc[1], 0, 0, 0);
      }
    }

    // epilogue (8 elems): z' = acc*fq + ev'; e=2^z'; r=1/(e+1); h127 = 127-254r
    // D layout row m=q*4+r, col nn (verified)
#pragma unroll
    for (int j = 0; j < 2; ++j) {
      const int col  = colbase + j * 16 + nn;     // global hidden col
      const int lcol = wave * 32 + j * 16 + nn;   // LDS-local col
#pragma unroll
      for (int r = 0; r < 4; ++r) {
        const int m = q * 4 + r;
        const float zp = fmaf((float)acc[j][r], fq, ev[j][r]);
        float e;
        asm("v_exp_f32 %0, %1" : "=v"(e) : "v"(zp));     // e = 2^zp = e^{2z}
        const float rr = __builtin_amdgcn_rcpf(e + 1.f);
        const int hi = __float2int_rn(fmaf(-254.f, rr, 127.f));
        hbuf[cur ^ 1][m][lcol] = (int8_t)hi;
        Hall[((size_t)(r0 + m) * SEQ + t) * HID + col] = (int8_t)hi;
        if (t == SEQ - 1)
          outH[(size_t)(r0 + m) * HID + col] = fmaf(-2.f, rr, 1.f);  // exact tanh
      }
    }

    // publish: syncthreads drains ALL waves' vmcnt/lgkmcnt (compiler-enforced),
    // then one thread makes stores agent-visible and releases the flag.
    __syncthreads();
    if (tid == 0) {
      __threadfence();   // write-back L2 so partner (other XCD) sees Hall h_t
      __hip_atomic_store(myflag, (unsigned)(t + 1), __ATOMIC_RELEASE,
                         __HIP_MEMORY_SCOPE_AGENT);
    }

#pragma unroll
    for (int r = 0; r < 4; ++r) tokc[r] = tokn[r];
    cur ^= 1;
  }
}

// Y[b,s,:] = (f_hh_h * f_ho) * (h_i8 @ Who_i8) + b_o  — fully parallel, i8 MFMA.
__global__ __launch_bounds__(256)
void ygemm_kernel(const int8_t* __restrict__ Hall,
                  const uint4* __restrict__ Wf8,
                  const float* __restrict__ sc,
                  const float* __restrict__ b_o,
                  float* __restrict__ out) {
  const int tid = threadIdx.x;
  const int wave = tid >> 6, lane = tid & 63;
  const int q = lane >> 4, nn = lane & 15;
  const size_t row0 = (size_t)blockIdx.x * 64 + (size_t)wave * 16;
  const float f = sc[1] * (1.f / (127.f * 127.f));
  i32x4 acc[8];
#pragma unroll
  for (int i = 0; i < 8; ++i) acc[i] = i32x4{0, 0, 0, 0};
  const int8_t* ha = Hall + (row0 + nn) * HID + q * 16;
  const uint4* wb = Wf8 + lane;
#pragma unroll
  for (int kt = 0; kt < 8; ++kt) {
    const i32x4 a = *(const i32x4*)(ha + kt * 64);
#pragma unroll
    for (int nt = 0; nt < 8; ++nt) {
      const i32x4 b = __builtin_bit_cast(i32x4, wb[(size_t)((32 + nt) * 8 + kt) * 64]);
      acc[nt] = __builtin_amdgcn_mfma_i32_16x16x64_i8(a, b, acc[nt], 0, 0, 0);
    }
  }
#pragma unroll
  for (int nt = 0; nt < 8; ++nt) {
    const float bo = b_o[nt * 16 + nn];
#pragma unroll
    for (int r = 0; r < 4; ++r)
      out[(row0 + q * 4 + r) * VOCAB + nt * 16 + nn] = (float)acc[nt][r] * f + bo;
  }
}

extern "C" void kernel_launch(void* const* d_in, const int* in_sizes, int n_in,
                              void* d_out, int out_size, void* d_ws, size_t ws_size,
                              hipStream_t stream) {
  const int*   x    = (const int*)d_in[0];
  const float* emb  = (const float*)d_in[1];
  const float* W_ih = (const float*)d_in[2];
  const float* b_ih = (const float*)d_in[3];
  const float* W_hh = (const float*)d_in[4];
  const float* b_hh = (const float*)d_in[5];
  const float* W_ho = (const float*)d_in[6];
  const float* b_o  = (const float*)d_in[7];
  float* out = (float*)d_out;

  char* ws = (char*)d_ws;
  float*        E      = (float*)ws;                        // 256 KB (E', 2log2e-scaled)
  uint4*        Wf8    = (uint4*)(ws + (256 << 10));        // 320 KB (40 nt x 8 x 1 KB)
  unsigned int* scu    = (unsigned int*)(ws + 589824);      // [0..1]=scales, [2..33]=flags
  const float*  scf    = (const float*)scu;
  unsigned int* flags  = scu + 2;                           // 32 step-flags (16 tiles x 2)
  int8_t*       Hall   = (int8_t*)(ws + (1 << 20));         // 64 MB i8

  hipMemsetAsync(scu, 0, 8 + 128, stream);   // ws is poisoned 0xAA every launch
  maxred_kernel<<<64, 256, 0, stream>>>(W_hh, HID * HID, scu + 0);
  maxred_kernel<<<16, 256, 0, stream>>>(W_ho, HID * VOCAB, scu + 1);
  eproj_kernel<<<VOCAB / 8, 512, 0, stream>>>(emb, W_ih, b_ih, b_hh, E);
  pack8_kernel<<<320, 64, 0, stream>>>(W_hh, W_ho, scf, Wf8);
  rnn_kernel<<<32, 512, 0, stream>>>(x, E, Wf8, scf, Hall,
                                     out + (size_t)BATCH * SEQ * VOCAB, flags);
  ygemm_kernel<<<(BATCH * SEQ) / 64, 256, 0, stream>>>(Hall, Wf8, scf, b_o, out);
}

// Round 10
// 871.792 us; speedup vs baseline: 4.0776x; 4.0776x over previous
//
#include <hip/hip_runtime.h>
#include <cstdint>
#include <cstddef>

#define BATCH 256
#define SEQ   512
#define HID   512
#define VOCAB 128

#define BT     16              // batch rows per block
#define HSTRB  528             // h-buffer row stride in BYTES (512 + 16, 16B-aligned)
#define LOG2E2 2.88539008177793f   // 2*log2(e): e^{2z} = 2^(z*LOG2E2), baked into E and fq

typedef __attribute__((ext_vector_type(4))) int   i32x4;
typedef __attribute__((ext_vector_type(4))) float f32x4;

// ---- fused prologue: eproj (blocks 0..15) + abs-max partials (blocks 16..55) ----
// eproj:  E'[v][j] = (sum_k emb[v][k]*W_ih[k][j] + b_ih[j] + b_hh[j]) * 2*log2(e)
// maxred: parts[0..31] = per-block max|W_hh| chunks, parts[32..39] = max|W_ho| chunks.
// Partials go to uniquely-owned slots -> no atomics, no memset prerequisite.
__global__ __launch_bounds__(512)
void prep_kernel(const float* __restrict__ emb,
                 const float* __restrict__ W_ih,
                 const float* __restrict__ b_ih,
                 const float* __restrict__ b_hh,
                 const float* __restrict__ W_hh,
                 const float* __restrict__ W_ho,
                 float* __restrict__ E,
                 float* __restrict__ parts) {
  __shared__ float es[8][64];     // eproj staging
  __shared__ float wmax[8];       // maxred wave partials
  const int bid = blockIdx.x;
  const int tid = threadIdx.x;

  if (bid < 16) {                 // ---- eproj (identical math to r8) ----
    const int j = tid;
    const int v0 = bid * 8;
    float acc[8];
#pragma unroll
    for (int v = 0; v < 8; ++v) acc[v] = 0.f;
    for (int k0 = 0; k0 < HID; k0 += 64) {
      __syncthreads();
      es[j >> 6][j & 63] = emb[(size_t)(v0 + (j >> 6)) * HID + k0 + (j & 63)];
      __syncthreads();
#pragma unroll 8
      for (int kk = 0; kk < 64; ++kk) {
        const float w = W_ih[(size_t)(k0 + kk) * HID + j];
#pragma unroll
        for (int v = 0; v < 8; ++v) acc[v] += es[v][kk] * w;
      }
    }
    const float bias = b_ih[j] + b_hh[j];
#pragma unroll
    for (int v = 0; v < 8; ++v)
      E[(size_t)(v0 + v) * HID + j] = (acc[v] + bias) * LOG2E2;
  } else {                        // ---- abs-max partial ----
    const bool hh = (bid < 48);
    const float* src = hh ? W_hh : W_ho;
    const int n     = hh ? HID * HID : HID * VOCAB;
    const int base  = hh ? (bid - 16) : (bid - 48);
    const int nb    = hh ? 32 : 8;
    float m = 0.f;
    for (int i = base * 512 + tid; i < n; i += nb * 512)
      m = fmaxf(m, fabsf(src[i]));
#pragma unroll
    for (int off = 32; off; off >>= 1)
      m = fmaxf(m, __shfl_down(m, off));
    if ((tid & 63) == 0) wmax[tid >> 6] = m;
    __syncthreads();
    if (tid == 0) {
      float mm = wmax[0];
#pragma unroll
      for (int w = 1; w < 8; ++w) mm = fmaxf(mm, wmax[w]);
      parts[bid - 16] = mm;       // slots 0..31 = W_hh, 32..39 = W_ho
    }
  }
}

// Pack [W_hh | W_ho] (512 x 640) into i8 MFMA B-fragments for 16x16x64.
// Fragment f = nt*8+kt8: lane l holds 16 i8 = B[k = kt8*64 + (l>>4)*16 + i][n = nt*16 + (l&15)]
// Reduces the 40 abs-max partials in-wave; block 0 materializes the scales for rnn/ygemm.
__global__ void pack8_kernel(const float* __restrict__ W_hh,
                             const float* __restrict__ W_ho,
                             const float* __restrict__ parts,
                             float* __restrict__ scf,        // [0]=max|W_hh|, [1]=max|W_ho|
                             uint4* __restrict__ Wf8) {
  const int f = blockIdx.x;            // 0..319 (40 nt * 8 kt8)
  const int nt = f >> 3, kt8 = f & 7;
  const int lane = threadIdx.x;
  const int q = lane >> 4, nn = lane & 15;
  const int n = nt * 16 + nn;

  float phh = parts[lane & 31];
#pragma unroll
  for (int off = 16; off; off >>= 1) phh = fmaxf(phh, __shfl_down(phh, off));
  const float s_hh = __shfl(phh, 0);
  float pho = parts[32 + (lane & 7)];
#pragma unroll
  for (int off = 4; off; off >>= 1) pho = fmaxf(pho, __shfl_down(pho, off));
  const float s_ho = __shfl(pho, 0);
  if (f == 0 && lane == 0) { scf[0] = s_hh; scf[1] = s_ho; }

  const float inv = 127.f / ((nt < 32) ? s_hh : s_ho);
  union { int8_t b[16]; uint4 u; } val;
#pragma unroll
  for (int i = 0; i < 16; ++i) {
    const int k = kt8 * 64 + q * 16 + i;
    const float w = (n < HID) ? W_hh[(size_t)k * HID + n]
                              : W_ho[(size_t)k * VOCAB + (n - HID)];
    val.b[i] = (int8_t)__float2int_rn(w * inv);
  }
  Wf8[(size_t)f * 64 + lane] = val.u;
}

// Recurrence: h_t = tanh(E[x_t] + h_{t-1} @ W_hh), all-i8 MFMA.  [VERBATIM r8 — control]
//  - hbuf double-buffered -> ONE barrier/step; wave B's K-loop overlaps wave A's epilogue.
//  - Folded tanh: z' = acc*fq' + E' (E',fq' carry 2*log2e); e=v_exp(z'); r=rcp(e+1);
//    h127 = 127 - 254*r.
// 16 blocks x 512 threads (8 waves, 2/SIMD); weights register-pinned (2 AGPR strips
// + 2 VGPR strips/wave). h i8 in LDS + streamed to Hall; separate ygemm pass.
__global__ __launch_bounds__(512, 2)
void rnn_kernel(const int* __restrict__ x,
                const float* __restrict__ E,
                const uint4* __restrict__ Wf8,
                const float* __restrict__ sc,
                int8_t* __restrict__ Hall,
                float* __restrict__ outH) {
  __shared__ __align__(16) int8_t hbuf[2][BT][HSTRB];   // 16.9 KB double-buffered

  const int tid = threadIdx.x;
  const int wave = tid >> 6, lane = tid & 63;
  const int q = lane >> 4, nn = lane & 15;
  const int r0 = blockIdx.x * BT;
  const float fq = sc[0] * (LOG2E2 / (127.f * 127.f));  // acc -> 2log2e * preact

  // 4 weight strips per wave (nt = wave*4+j): j<2 in AGPR, j>=2 in VGPR; pinned.
  i32x4 wa[2][8], wv[2][8];
  {
    const uint4* wb = Wf8 + lane;
#pragma unroll
    for (int j = 0; j < 2; ++j)
#pragma unroll
      for (int kt = 0; kt < 8; ++kt)
        wa[j][kt] = __builtin_bit_cast(i32x4, wb[(size_t)((wave * 4 + j) * 8 + kt) * 64]);
#pragma unroll
    for (int j = 0; j < 2; ++j)
#pragma unroll
      for (int kt = 0; kt < 8; ++kt)
        wv[j][kt] = __builtin_bit_cast(i32x4, wb[(size_t)((wave * 4 + 2 + j) * 8 + kt) * 64]);
  }
#pragma unroll
  for (int j = 0; j < 2; ++j)
#pragma unroll
    for (int kt = 0; kt < 8; ++kt)
      asm volatile("" : "+a"(wa[j][kt]));
#pragma unroll
  for (int j = 0; j < 2; ++j)
#pragma unroll
    for (int kt = 0; kt < 8; ++kt)
      asm volatile("" : "+v"(wv[j][kt]));

  // token prefetch for t=0
  int tokc[4];
#pragma unroll
  for (int r = 0; r < 4; ++r) tokc[r] = x[(size_t)(r0 + q * 4 + r) * SEQ + 0];

  int cur = 0;
  for (int t = 0; t < SEQ; ++t) {
    int tokn[4];
    const int tn = (t + 1 < SEQ) ? t + 1 : t;
#pragma unroll
    for (int r = 0; r < 4; ++r) tokn[r] = x[(size_t)(r0 + q * 4 + r) * SEQ + tn];

    // E' rows for this step's epilogue (K-loop hides the gather latency)
    float ev[4][4];
#pragma unroll
    for (int j = 0; j < 4; ++j)
#pragma unroll
      for (int r = 0; r < 4; ++r)
        ev[j][r] = E[(size_t)tokc[r] * HID + wave * 64 + j * 16 + nn];

    i32x4 acc[4];
#pragma unroll
    for (int j = 0; j < 4; ++j) acc[j] = i32x4{0, 0, 0, 0};

    if (t > 0) {
#pragma unroll
      for (int kt = 0; kt < 8; ++kt) {
        const i32x4 a = *(const i32x4*)&hbuf[cur][nn][kt * 64 + q * 16];
        acc[0] = __builtin_amdgcn_mfma_i32_16x16x64_i8(a, wa[0][kt], acc[0], 0, 0, 0);
        acc[1] = __builtin_amdgcn_mfma_i32_16x16x64_i8(a, wa[1][kt], acc[1], 0, 0, 0);
        acc[2] = __builtin_amdgcn_mfma_i32_16x16x64_i8(a, wv[0][kt], acc[2], 0, 0, 0);
        acc[3] = __builtin_amdgcn_mfma_i32_16x16x64_i8(a, wv[1][kt], acc[3], 0, 0, 0);
      }
    }
    // NO barrier here: epilogue writes go to buf[cur^1] (disjoint from reads of buf[cur])

    // epilogue: z' = acc*fq + ev' (carries 2log2e); e=2^z'; r=1/(e+1);
    // h127 = 127 - 254r;  D layout row m=q*4+r, col nn (verified)
#pragma unroll
    for (int j = 0; j < 4; ++j) {
      const int col = wave * 64 + j * 16 + nn;
#pragma unroll
      for (int r = 0; r < 4; ++r) {
        const int m = q * 4 + r;
        const float zp = fmaf((float)acc[j][r], fq, ev[j][r]);
        float e;
        asm("v_exp_f32 %0, %1" : "=v"(e) : "v"(zp));     // e = 2^zp = e^{2z}
        const float rr = __builtin_amdgcn_rcpf(e + 1.f);
        const int hi = __float2int_rn(fmaf(-254.f, rr, 127.f));
        hbuf[cur ^ 1][m][col] = (int8_t)hi;
        Hall[((size_t)(r0 + m) * SEQ + t) * HID + col] = (int8_t)hi;
        if (t == SEQ - 1)
          outH[(size_t)(r0 + m) * HID + col] = fmaf(-2.f, rr, 1.f);  // exact tanh value
      }
    }
    // single per-step sync: drain this wave's LDS reads+writes, publish buf[cur^1]
    asm volatile("s_waitcnt lgkmcnt(0)\n\ts_barrier" ::: "memory");

#pragma unroll
    for (int r = 0; r < 4; ++r) tokc[r] = tokn[r];
    cur ^= 1;
  }
}

// Y[b,s,:] = (f_hh_h * f_ho) * (h_i8 @ Who_i8) + b_o  — fully parallel, i8 MFMA.
__global__ __launch_bounds__(256)
void ygemm_kernel(const int8_t* __restrict__ Hall,
                  const uint4* __restrict__ Wf8,
                  const float* __restrict__ sc,
                  const float* __restrict__ b_o,
                  float* __restrict__ out) {
  const int tid = threadIdx.x;
  const int wave = tid >> 6, lane = tid & 63;
  const int q = lane >> 4, nn = lane & 15;
  const size_t row0 = (size_t)blockIdx.x * 64 + (size_t)wave * 16;
  const float f = sc[1] * (1.f / (127.f * 127.f));
  i32x4 acc[8];
#pragma unroll
  for (int i = 0; i < 8; ++i) acc[i] = i32x4{0, 0, 0, 0};
  const int8_t* ha = Hall + (row0 + nn) * HID + q * 16;
  const uint4* wb = Wf8 + lane;
#pragma unroll
  for (int kt = 0; kt < 8; ++kt) {
    const i32x4 a = *(const i32x4*)(ha + kt * 64);
#pragma unroll
    for (int nt = 0; nt < 8; ++nt) {
      const i32x4 b = __builtin_bit_cast(i32x4, wb[(size_t)((32 + nt) * 8 + kt) * 64]);
      acc[nt] = __builtin_amdgcn_mfma_i32_16x16x64_i8(a, b, acc[nt], 0, 0, 0);
    }
  }
#pragma unroll
  for (int nt = 0; nt < 8; ++nt) {
    const float bo = b_o[nt * 16 + nn];
#pragma unroll
    for (int r = 0; r < 4; ++r)
      out[(row0 + q * 4 + r) * VOCAB + nt * 16 + nn] = (float)acc[nt][r] * f + bo;
  }
}

extern "C" void kernel_launch(void* const* d_in, const int* in_sizes, int n_in,
                              void* d_out, int out_size, void* d_ws, size_t ws_size,
                              hipStream_t stream) {
  const int*   x    = (const int*)d_in[0];
  const float* emb  = (const float*)d_in[1];
  const float* W_ih = (const float*)d_in[2];
  const float* b_ih = (const float*)d_in[3];
  const float* W_hh = (const float*)d_in[4];
  const float* b_hh = (const float*)d_in[5];
  const float* W_ho = (const float*)d_in[6];
  const float* b_o  = (const float*)d_in[7];
  float* out = (float*)d_out;

  char* ws = (char*)d_ws;
  float*        E      = (float*)ws;                        // 256 KB (E', 2log2e-scaled)
  uint4*        Wf8    = (uint4*)(ws + (256 << 10));        // 320 KB (40 nt x 8 x 1 KB)
  float*        scf    = (float*)(ws + 589824);             // [0..1] scales
  float*        parts  = scf + 2;                           // [0..39] abs-max partials
  int8_t*       Hall   = (int8_t*)(ws + (1 << 20));         // 64 MB i8

  // 4 dispatches, no memset (every ws slot written before read; ws poison harmless):
  // prep (eproj + maxred partials, concurrent) -> pack8 (reduces partials, packs)
  // -> rnn -> ygemm
  prep_kernel<<<56, 512, 0, stream>>>(emb, W_ih, b_ih, b_hh, W_hh, W_ho, E, parts);
  pack8_kernel<<<320, 64, 0, stream>>>(W_hh, W_ho, parts, scf, Wf8);
  rnn_kernel<<<16, 512, 0, stream>>>(x, E, Wf8, scf, Hall,
                                     out + (size_t)BATCH * SEQ * VOCAB);
  ygemm_kernel<<<(BATCH * SEQ) / 64, 256, 0, stream>>>(Hall, Wf8, scf, b_o, out);
}

// Round 12
// 792.549 us; speedup vs baseline: 4.4853x; 1.1000x over previous
//
#include <hip/hip_runtime.h>
#include <cstdint>
#include <cstddef>

#define BATCH 256
#define SEQ   512
#define HID   512
#define VOCAB 128

#define BT     16              // batch rows per block
#define HSTRB  528             // h-buffer row stride in BYTES (512 + 16, 16B-aligned)
#define LOG2E2 2.88539008177793f   // 2*log2(e): e^{2z} = 2^(z*LOG2E2), baked into E and fq

typedef __attribute__((ext_vector_type(4))) int   i32x4;
typedef __attribute__((ext_vector_type(4))) float f32x4;

// ---- fused prologue: eproj (blocks 0..15) + abs-max partials (blocks 16..55) ----
__global__ __launch_bounds__(512)
void prep_kernel(const float* __restrict__ emb,
                 const float* __restrict__ W_ih,
                 const float* __restrict__ b_ih,
                 const float* __restrict__ b_hh,
                 const float* __restrict__ W_hh,
                 const float* __restrict__ W_ho,
                 float* __restrict__ E,
                 float* __restrict__ parts) {
  __shared__ float es[8][64];     // eproj staging
  __shared__ float wmax[8];       // maxred wave partials
  const int bid = blockIdx.x;
  const int tid = threadIdx.x;

  if (bid < 16) {                 // ---- eproj ----
    const int j = tid;
    const int v0 = bid * 8;
    float acc[8];
#pragma unroll
    for (int v = 0; v < 8; ++v) acc[v] = 0.f;
    for (int k0 = 0; k0 < HID; k0 += 64) {
      __syncthreads();
      es[j >> 6][j & 63] = emb[(size_t)(v0 + (j >> 6)) * HID + k0 + (j & 63)];
      __syncthreads();
#pragma unroll 8
      for (int kk = 0; kk < 64; ++kk) {
        const float w = W_ih[(size_t)(k0 + kk) * HID + j];
#pragma unroll
        for (int v = 0; v < 8; ++v) acc[v] += es[v][kk] * w;
      }
    }
    const float bias = b_ih[j] + b_hh[j];
#pragma unroll
    for (int v = 0; v < 8; ++v)
      E[(size_t)(v0 + v) * HID + j] = (acc[v] + bias) * LOG2E2;
  } else {                        // ---- abs-max partial ----
    const bool hh = (bid < 48);
    const float* src = hh ? W_hh : W_ho;
    const int n     = hh ? HID * HID : HID * VOCAB;
    const int base  = hh ? (bid - 16) : (bid - 48);
    const int nb    = hh ? 32 : 8;
    float m = 0.f;
    for (int i = base * 512 + tid; i < n; i += nb * 512)
      m = fmaxf(m, fabsf(src[i]));
#pragma unroll
    for (int off = 32; off; off >>= 1)
      m = fmaxf(m, __shfl_down(m, off));
    if ((tid & 63) == 0) wmax[tid >> 6] = m;
    __syncthreads();
    if (tid == 0) {
      float mm = wmax[0];
#pragma unroll
      for (int w = 1; w < 8; ++w) mm = fmaxf(mm, wmax[w]);
      parts[bid - 16] = mm;       // slots 0..31 = W_hh, 32..39 = W_ho
    }
  }
}

// Pack [W_hh | W_ho] (512 x 640) into i8 MFMA B-fragments for 16x16x64, with the
// k-axis PERMUTED to match the dword-packed h storage: storage address c within
// each 64-k block holds true unit (c&3)*16 + (c>>2)  (rnn epilogue writes thread
// (j,nn)'s 4 bytes {j=0..3} contiguously at nn*4). Fragment slot (q,i) is address
// c = q*16+i  =>  k_true = kt8*64 + (i&3)*16 + q*4 + (i>>2).
// Both consumers (rnn K-loop A from hbuf, ygemm A from Hall) read the same
// permuted storage, so the contraction stays correct.
__global__ void pack8_kernel(const float* __restrict__ W_hh,
                             const float* __restrict__ W_ho,
                             const float* __restrict__ parts,
                             float* __restrict__ scf,        // [0]=max|W_hh|, [1]=max|W_ho|
                             uint4* __restrict__ Wf8) {
  const int f = blockIdx.x;            // 0..319 (40 nt * 8 kt8)
  const int nt = f >> 3, kt8 = f & 7;
  const int lane = threadIdx.x;
  const int q = lane >> 4, nn = lane & 15;
  const int n = nt * 16 + nn;

  float phh = parts[lane & 31];
#pragma unroll
  for (int off = 16; off; off >>= 1) phh = fmaxf(phh, __shfl_down(phh, off));
  const float s_hh = __shfl(phh, 0);
  float pho = parts[32 + (lane & 7)];
#pragma unroll
  for (int off = 4; off; off >>= 1) pho = fmaxf(pho, __shfl_down(pho, off));
  const float s_ho = __shfl(pho, 0);
  if (f == 0 && lane == 0) { scf[0] = s_hh; scf[1] = s_ho; }

  const float inv = 127.f / ((nt < 32) ? s_hh : s_ho);
  union { int8_t b[16]; uint4 u; } val;
#pragma unroll
  for (int i = 0; i < 16; ++i) {
    const int k = kt8 * 64 + (i & 3) * 16 + q * 4 + (i >> 2);   // k-permutation
    const float w = (n < HID) ? W_hh[(size_t)k * HID + n]
                              : W_ho[(size_t)k * VOCAB + (n - HID)];
    val.b[i] = (int8_t)__float2int_rn(w * inv);
  }
  Wf8[(size_t)f * 64 + lane] = val.u;
}

// Recurrence: h_t = tanh(E[x_t] + h_{t-1} @ W_hh), all-i8 MFMA.  [r8 structure]
// NEW vs r10: epilogue packs each row's 4 h-bytes into ONE dword (ds_write_b32 +
// dword Hall store at col addr wave*64 + nn*4) instead of 4+4 scattered byte
// stores — 16->4 stores per destination per thread per step. Enabled by the
// pack8 k-permutation above; E/outH stay in true-unit order (D-cols unpermuted).
__global__ __launch_bounds__(512, 2)
void rnn_kernel(const int* __restrict__ x,
                const float* __restrict__ E,
                const uint4* __restrict__ Wf8,
                const float* __restrict__ sc,
                int8_t* __restrict__ Hall,
                float* __restrict__ outH) {
  __shared__ __align__(16) int8_t hbuf[2][BT][HSTRB];   // 16.9 KB double-buffered

  const int tid = threadIdx.x;
  const int wave = tid >> 6, lane = tid & 63;
  const int q = lane >> 4, nn = lane & 15;
  const int r0 = blockIdx.x * BT;
  const float fq = sc[0] * (LOG2E2 / (127.f * 127.f));  // acc -> 2log2e * preact

  // 4 weight strips per wave (nt = wave*4+j): j<2 in AGPR, j>=2 in VGPR; pinned.
  i32x4 wa[2][8], wv[2][8];
  {
    const uint4* wb = Wf8 + lane;
#pragma unroll
    for (int j = 0; j < 2; ++j)
#pragma unroll
      for (int kt = 0; kt < 8; ++kt)
        wa[j][kt] = __builtin_bit_cast(i32x4, wb[(size_t)((wave * 4 + j) * 8 + kt) * 64]);
#pragma unroll
    for (int j = 0; j < 2; ++j)
#pragma unroll
      for (int kt = 0; kt < 8; ++kt)
        wv[j][kt] = __builtin_bit_cast(i32x4, wb[(size_t)((wave * 4 + 2 + j) * 8 + kt) * 64]);
  }
#pragma unroll
  for (int j = 0; j < 2; ++j)
#pragma unroll
    for (int kt = 0; kt < 8; ++kt)
      asm volatile("" : "+a"(wa[j][kt]));
#pragma unroll
  for (int j = 0; j < 2; ++j)
#pragma unroll
    for (int kt = 0; kt < 8; ++kt)
      asm volatile("" : "+v"(wv[j][kt]));

  // token prefetch for t=0
  int tokc[4];
#pragma unroll
  for (int r = 0; r < 4; ++r) tokc[r] = x[(size_t)(r0 + q * 4 + r) * SEQ + 0];

  int cur = 0;
  for (int t = 0; t < SEQ; ++t) {
    int tokn[4];
    const int tn = (t + 1 < SEQ) ? t + 1 : t;
#pragma unroll
    for (int r = 0; r < 4; ++r) tokn[r] = x[(size_t)(r0 + q * 4 + r) * SEQ + tn];

    // E' rows for this step's epilogue (true-unit cols; K-loop hides latency)
    float ev[4][4];
#pragma unroll
    for (int j = 0; j < 4; ++j)
#pragma unroll
      for (int r = 0; r < 4; ++r)
        ev[j][r] = E[(size_t)tokc[r] * HID + wave * 64 + j * 16 + nn];

    i32x4 acc[4];
#pragma unroll
    for (int j = 0; j < 4; ++j) acc[j] = i32x4{0, 0, 0, 0};

    if (t > 0) {
#pragma unroll
      for (int kt = 0; kt < 8; ++kt) {
        const i32x4 a = *(const i32x4*)&hbuf[cur][nn][kt * 64 + q * 16];
        acc[0] = __builtin_amdgcn_mfma_i32_16x16x64_i8(a, wa[0][kt], acc[0], 0, 0, 0);
        acc[1] = __builtin_amdgcn_mfma_i32_16x16x64_i8(a, wa[1][kt], acc[1], 0, 0, 0);
        acc[2] = __builtin_amdgcn_mfma_i32_16x16x64_i8(a, wv[0][kt], acc[2], 0, 0, 0);
        acc[3] = __builtin_amdgcn_mfma_i32_16x16x64_i8(a, wv[1][kt], acc[3], 0, 0, 0);
      }
    }
    // NO barrier here: epilogue writes go to buf[cur^1] (disjoint from reads of buf[cur])

    // epilogue (r-outer, j-inner): z' = acc*fq + ev'; e=2^z'; rr=rcp(e+1);
    // byte j of row m's dword = 127-254rr; one ds_write_b32 + one Hall dword per m.
    // D layout row m=q*4+r, col j*16+nn (true unit); storage addr nn*4+j (permuted).
#pragma unroll
    for (int r = 0; r < 4; ++r) {
      const int m = q * 4 + r;
      uint32_t hp = 0;
#pragma unroll
      for (int j = 0; j < 4; ++j) {
        const float zp = fmaf((float)acc[j][r], fq, ev[j][r]);
        float e;
        asm("v_exp_f32 %0, %1" : "=v"(e) : "v"(zp));     // e = 2^zp = e^{2z}
        const float rr = __builtin_amdgcn_rcpf(e + 1.f);
        const int hi = __float2int_rn(fmaf(-254.f, rr, 127.f));
        hp |= ((uint32_t)hi & 0xffu) << (8 * j);
        if (t == SEQ - 1)   // exact fp32 h at TRUE col (unpermuted out layout)
          outH[(size_t)(r0 + m) * HID + wave * 64 + j * 16 + nn] = fmaf(-2.f, rr, 1.f);
      }
      *(uint32_t*)&hbuf[cur ^ 1][m][wave * 64 + nn * 4] = hp;
      *(uint32_t*)&Hall[((size_t)(r0 + m) * SEQ + t) * HID + wave * 64 + nn * 4] = hp;
    }
    // single per-step sync: drain LDS writes, publish buf[cur^1]; Hall stores keep flying
    asm volatile("s_waitcnt lgkmcnt(0)\n\ts_barrier" ::: "memory");

#pragma unroll
    for (int r = 0; r < 4; ++r) tokc[r] = tokn[r];
    cur ^= 1;
  }
}

// Y[b,s,:] = (f_hh_h * f_ho) * (h_i8 @ Who_i8) + b_o  — fully parallel, i8 MFMA.
// Reads Hall's permuted storage; Wf8's W_ho fragments carry the matching k-perm.
__global__ __launch_bounds__(256)
void ygemm_kernel(const int8_t* __restrict__ Hall,
                  const uint4* __restrict__ Wf8,
                  const float* __restrict__ sc,
                  const float* __restrict__ b_o,
                  float* __restrict__ out) {
  const int tid = threadIdx.x;
  const int wave = tid >> 6, lane = tid & 63;
  const int q = lane >> 4, nn = lane & 15;
  const size_t row0 = (size_t)blockIdx.x * 64 + (size_t)wave * 16;
  const float f = sc[1] * (1.f / (127.f * 127.f));
  i32x4 acc[8];
#pragma unroll
  for (int i = 0; i < 8; ++i) acc[i] = i32x4{0, 0, 0, 0};
  const int8_t* ha = Hall + (row0 + nn) * HID + q * 16;
  const uint4* wb = Wf8 + lane;
#pragma unroll
  for (int kt = 0; kt < 8; ++kt) {
    const i32x4 a = *(const i32x4*)(ha + kt * 64);
#pragma unroll
    for (int nt = 0; nt < 8; ++nt) {
      const i32x4 b = __builtin_bit_cast(i32x4, wb[(size_t)((32 + nt) * 8 + kt) * 64]);
      acc[nt] = __builtin_amdgcn_mfma_i32_16x16x64_i8(a, b, acc[nt], 0, 0, 0);
    }
  }
#pragma unroll
  for (int nt = 0; nt < 8; ++nt) {
    const float bo = b_o[nt * 16 + nn];
#pragma unroll
    for (int r = 0; r < 4; ++r)
      out[(row0 + q * 4 + r) * VOCAB + nt * 16 + nn] = (float)acc[nt][r] * f + bo;
  }
}

extern "C" void kernel_launch(void* const* d_in, const int* in_sizes, int n_in,
                              void* d_out, int out_size, void* d_ws, size_t ws_size,
                              hipStream_t stream) {
  const int*   x    = (const int*)d_in[0];
  const float* emb  = (const float*)d_in[1];
  const float* W_ih = (const float*)d_in[2];
  const float* b_ih = (const float*)d_in[3];
  const float* W_hh = (const float*)d_in[4];
  const float* b_hh = (const float*)d_in[5];
  const float* W_ho = (const float*)d_in[6];
  const float* b_o  = (const float*)d_in[7];
  float* out = (float*)d_out;

  char* ws = (char*)d_ws;
  float*        E      = (float*)ws;                        // 256 KB (E', 2log2e-scaled)
  uint4*        Wf8    = (uint4*)(ws + (256 << 10));        // 320 KB (40 nt x 8 x 1 KB)
  float*        scf    = (float*)(ws + 589824);             // [0..1] scales
  float*        parts  = scf + 2;                           // [0..39] abs-max partials
  int8_t*       Hall   = (int8_t*)(ws + (1 << 20));         // 64 MB i8 (k-permuted cols)

  prep_kernel<<<56, 512, 0, stream>>>(emb, W_ih, b_ih, b_hh, W_hh, W_ho, E, parts);
  pack8_kernel<<<320, 64, 0, stream>>>(W_hh, W_ho, parts, scf, Wf8);
  rnn_kernel<<<16, 512, 0, stream>>>(x, E, Wf8, scf, Hall,
                                     out + (size_t)BATCH * SEQ * VOCAB);
  ygemm_kernel<<<(BATCH * SEQ) / 64, 256, 0, stream>>>(Hall, Wf8, scf, b_o, out);
}

// Round 13
// 732.381 us; speedup vs baseline: 4.8538x; 1.0822x over previous
//
#include <hip/hip_runtime.h>
#include <cstdint>
#include <cstddef>

#define BATCH 256
#define SEQ   512
#define HID   512
#define VOCAB 128

#define BT     16              // batch rows per block
#define HSTRB  528             // h-buffer row stride in BYTES (512 + 16, 16B-aligned)
#define LOG2E2 2.88539008177793f   // 2*log2(e): e^{2z} = 2^(z*LOG2E2), baked into E and fq

typedef __attribute__((ext_vector_type(4))) int   i32x4;
typedef __attribute__((ext_vector_type(4))) float f32x4;

// ---- fused prologue: eproj (blocks 0..15) + abs-max partials (blocks 16..55) ----
// E is written PERMUTED within each 64-col group: true unit u = jj*16+nn stored at
// addr nn*4+jj, so the rnn epilogue reads its 4 j-values as ONE float4.
__global__ __launch_bounds__(512)
void prep_kernel(const float* __restrict__ emb,
                 const float* __restrict__ W_ih,
                 const float* __restrict__ b_ih,
                 const float* __restrict__ b_hh,
                 const float* __restrict__ W_hh,
                 const float* __restrict__ W_ho,
                 float* __restrict__ E,
                 float* __restrict__ parts) {
  __shared__ float es[8][64];     // eproj staging
  __shared__ float wmax[8];       // maxred wave partials
  const int bid = blockIdx.x;
  const int tid = threadIdx.x;

  if (bid < 16) {                 // ---- eproj ----
    const int j = tid;            // true unit index
    const int v0 = bid * 8;
    float acc[8];
#pragma unroll
    for (int v = 0; v < 8; ++v) acc[v] = 0.f;
    for (int k0 = 0; k0 < HID; k0 += 64) {
      __syncthreads();
      es[j >> 6][j & 63] = emb[(size_t)(v0 + (j >> 6)) * HID + k0 + (j & 63)];
      __syncthreads();
#pragma unroll 8
      for (int kk = 0; kk < 64; ++kk) {
        const float w = W_ih[(size_t)(k0 + kk) * HID + j];
#pragma unroll
        for (int v = 0; v < 8; ++v) acc[v] += es[v][kk] * w;
      }
    }
    const float bias = b_ih[j] + b_hh[j];
    // permuted store address: group | nn*4 | jj
    const int pj = (j & ~63) | ((j & 15) << 2) | ((j >> 4) & 3);
#pragma unroll
    for (int v = 0; v < 8; ++v)
      E[(size_t)(v0 + v) * HID + pj] = (acc[v] + bias) * LOG2E2;
  } else {                        // ---- abs-max partial ----
    const bool hh = (bid < 48);
    const float* src = hh ? W_hh : W_ho;
    const int n     = hh ? HID * HID : HID * VOCAB;
    const int base  = hh ? (bid - 16) : (bid - 48);
    const int nb    = hh ? 32 : 8;
    float m = 0.f;
    for (int i = base * 512 + tid; i < n; i += nb * 512)
      m = fmaxf(m, fabsf(src[i]));
#pragma unroll
    for (int off = 32; off; off >>= 1)
      m = fmaxf(m, __shfl_down(m, off));
    if ((tid & 63) == 0) wmax[tid >> 6] = m;
    __syncthreads();
    if (tid == 0) {
      float mm = wmax[0];
#pragma unroll
      for (int w = 1; w < 8; ++w) mm = fmaxf(mm, wmax[w]);
      parts[bid - 16] = mm;       // slots 0..31 = W_hh, 32..39 = W_ho
    }
  }
}

// Pack [W_hh | W_ho] (512 x 640) into i8 MFMA B-fragments for 16x16x64, with the
// k-axis PERMUTED to match the dword-packed h storage: storage address c within
// each 64-k block holds true unit (c&3)*16 + (c>>2). Fragment slot (q,i) is
// address c = q*16+i  =>  k_true = kt8*64 + (i&3)*16 + q*4 + (i>>2).
__global__ void pack8_kernel(const float* __restrict__ W_hh,
                             const float* __restrict__ W_ho,
                             const float* __restrict__ parts,
                             float* __restrict__ scf,        // [0]=max|W_hh|, [1]=max|W_ho|
                             uint4* __restrict__ Wf8) {
  const int f = blockIdx.x;            // 0..319 (40 nt * 8 kt8)
  const int nt = f >> 3, kt8 = f & 7;
  const int lane = threadIdx.x;
  const int q = lane >> 4, nn = lane & 15;
  const int n = nt * 16 + nn;

  float phh = parts[lane & 31];
#pragma unroll
  for (int off = 16; off; off >>= 1) phh = fmaxf(phh, __shfl_down(phh, off));
  const float s_hh = __shfl(phh, 0);
  float pho = parts[32 + (lane & 7)];
#pragma unroll
  for (int off = 4; off; off >>= 1) pho = fmaxf(pho, __shfl_down(pho, off));
  const float s_ho = __shfl(pho, 0);
  if (f == 0 && lane == 0) { scf[0] = s_hh; scf[1] = s_ho; }

  const float inv = 127.f / ((nt < 32) ? s_hh : s_ho);
  union { int8_t b[16]; uint4 u; } val;
#pragma unroll
  for (int i = 0; i < 16; ++i) {
    const int k = kt8 * 64 + (i & 3) * 16 + q * 4 + (i >> 2);   // k-permutation
    const float w = (n < HID) ? W_hh[(size_t)k * HID + n]
                              : W_ho[(size_t)k * VOCAB + (n - HID)];
    val.b[i] = (int8_t)__float2int_rn(w * inv);
  }
  Wf8[(size_t)f * 64 + lane] = val.u;
}

// Recurrence: h_t = tanh(E[x_t] + h_{t-1} @ W_hh), all-i8 MFMA.  [r12 structure]
// NEW vs r12 (same lever class — epilogue issue/addressing reduction):
//  1. E reads: 4 x float4 (permuted E storage) instead of 16 scalar loads.
//  2. Hall stores: 4 persistent pointers advanced by HID/step — no per-step mad64.
__global__ __launch_bounds__(512, 2)
void rnn_kernel(const int* __restrict__ x,
                const float* __restrict__ E,
                const uint4* __restrict__ Wf8,
                const float* __restrict__ sc,
                int8_t* __restrict__ Hall,
                float* __restrict__ outH) {
  __shared__ __align__(16) int8_t hbuf[2][BT][HSTRB];   // 16.9 KB double-buffered

  const int tid = threadIdx.x;
  const int wave = tid >> 6, lane = tid & 63;
  const int q = lane >> 4, nn = lane & 15;
  const int r0 = blockIdx.x * BT;
  const float fq = sc[0] * (LOG2E2 / (127.f * 127.f));  // acc -> 2log2e * preact

  // 4 weight strips per wave (nt = wave*4+j): j<2 in AGPR, j>=2 in VGPR; pinned.
  i32x4 wa[2][8], wv[2][8];
  {
    const uint4* wb = Wf8 + lane;
#pragma unroll
    for (int j = 0; j < 2; ++j)
#pragma unroll
      for (int kt = 0; kt < 8; ++kt)
        wa[j][kt] = __builtin_bit_cast(i32x4, wb[(size_t)((wave * 4 + j) * 8 + kt) * 64]);
#pragma unroll
    for (int j = 0; j < 2; ++j)
#pragma unroll
      for (int kt = 0; kt < 8; ++kt)
        wv[j][kt] = __builtin_bit_cast(i32x4, wb[(size_t)((wave * 4 + 2 + j) * 8 + kt) * 64]);
  }
#pragma unroll
  for (int j = 0; j < 2; ++j)
#pragma unroll
    for (int kt = 0; kt < 8; ++kt)
      asm volatile("" : "+a"(wa[j][kt]));
#pragma unroll
  for (int j = 0; j < 2; ++j)
#pragma unroll
    for (int kt = 0; kt < 8; ++kt)
      asm volatile("" : "+v"(wv[j][kt]));

  // persistent Hall write pointers (advance by HID bytes/step; saves per-step mad64)
  uint32_t* hallp[4];
#pragma unroll
  for (int r = 0; r < 4; ++r)
    hallp[r] = (uint32_t*)(Hall + (size_t)(r0 + q * 4 + r) * SEQ * HID + wave * 64 + nn * 4);

  // token prefetch for t=0
  int tokc[4];
#pragma unroll
  for (int r = 0; r < 4; ++r) tokc[r] = x[(size_t)(r0 + q * 4 + r) * SEQ + 0];

  int cur = 0;
  for (int t = 0; t < SEQ; ++t) {
    int tokn[4];
    const int tn = (t + 1 < SEQ) ? t + 1 : t;
#pragma unroll
    for (int r = 0; r < 4; ++r) tokn[r] = x[(size_t)(r0 + q * 4 + r) * SEQ + tn];

    // E' rows: ONE float4 per token (permuted storage: addr nn*4+j holds unit j*16+nn)
    f32x4 ev4[4];
#pragma unroll
    for (int r = 0; r < 4; ++r)
      ev4[r] = *(const f32x4*)&E[(size_t)tokc[r] * HID + wave * 64 + nn * 4];

    i32x4 acc[4];
#pragma unroll
    for (int j = 0; j < 4; ++j) acc[j] = i32x4{0, 0, 0, 0};

    if (t > 0) {
#pragma unroll
      for (int kt = 0; kt < 8; ++kt) {
        const i32x4 a = *(const i32x4*)&hbuf[cur][nn][kt * 64 + q * 16];
        acc[0] = __builtin_amdgcn_mfma_i32_16x16x64_i8(a, wa[0][kt], acc[0], 0, 0, 0);
        acc[1] = __builtin_amdgcn_mfma_i32_16x16x64_i8(a, wa[1][kt], acc[1], 0, 0, 0);
        acc[2] = __builtin_amdgcn_mfma_i32_16x16x64_i8(a, wv[0][kt], acc[2], 0, 0, 0);
        acc[3] = __builtin_amdgcn_mfma_i32_16x16x64_i8(a, wv[1][kt], acc[3], 0, 0, 0);
      }
    }
    // NO barrier here: epilogue writes go to buf[cur^1] (disjoint from reads of buf[cur])

    // epilogue (r-outer, j-inner): z' = acc*fq + ev4; e=2^z'; rr=rcp(e+1);
    // byte j of row m's dword = 127-254rr; one ds_write_b32 + one Hall dword per m.
#pragma unroll
    for (int r = 0; r < 4; ++r) {
      const int m = q * 4 + r;
      uint32_t hp = 0;
#pragma unroll
      for (int j = 0; j < 4; ++j) {
        const float zp = fmaf((float)acc[j][r], fq, ev4[r][j]);
        float e;
        asm("v_exp_f32 %0, %1" : "=v"(e) : "v"(zp));     // e = 2^zp = e^{2z}
        const float rr = __builtin_amdgcn_rcpf(e + 1.f);
        const int hi = __float2int_rn(fmaf(-254.f, rr, 127.f));
        hp |= ((uint32_t)hi & 0xffu) << (8 * j);
        if (t == SEQ - 1)   // exact fp32 h at TRUE col (unpermuted out layout)
          outH[(size_t)(r0 + m) * HID + wave * 64 + j * 16 + nn] = fmaf(-2.f, rr, 1.f);
      }
      *(uint32_t*)&hbuf[cur ^ 1][m][wave * 64 + nn * 4] = hp;
      *hallp[r] = hp;
      hallp[r] += HID / 4;
    }
    // single per-step sync: drain LDS writes, publish buf[cur^1]; Hall stores keep flying
    asm volatile("s_waitcnt lgkmcnt(0)\n\ts_barrier" ::: "memory");

#pragma unroll
    for (int r = 0; r < 4; ++r) tokc[r] = tokn[r];
    cur ^= 1;
  }
}

// Y[b,s,:] = (f_hh_h * f_ho) * (h_i8 @ Who_i8) + b_o  — fully parallel, i8 MFMA.
// Reads Hall's permuted storage; Wf8's W_ho fragments carry the matching k-perm.
__global__ __launch_bounds__(256)
void ygemm_kernel(const int8_t* __restrict__ Hall,
                  const uint4* __restrict__ Wf8,
                  const float* __restrict__ sc,
                  const float* __restrict__ b_o,
                  float* __restrict__ out) {
  const int tid = threadIdx.x;
  const int wave = tid >> 6, lane = tid & 63;
  const int q = lane >> 4, nn = lane & 15;
  const size_t row0 = (size_t)blockIdx.x * 64 + (size_t)wave * 16;
  const float f = sc[1] * (1.f / (127.f * 127.f));
  i32x4 acc[8];
#pragma unroll
  for (int i = 0; i < 8; ++i) acc[i] = i32x4{0, 0, 0, 0};
  const int8_t* ha = Hall + (row0 + nn) * HID + q * 16;
  const uint4* wb = Wf8 + lane;
#pragma unroll
  for (int kt = 0; kt < 8; ++kt) {
    const i32x4 a = *(const i32x4*)(ha + kt * 64);
#pragma unroll
    for (int nt = 0; nt < 8; ++nt) {
      const i32x4 b = __builtin_bit_cast(i32x4, wb[(size_t)((32 + nt) * 8 + kt) * 64]);
      acc[nt] = __builtin_amdgcn_mfma_i32_16x16x64_i8(a, b, acc[nt], 0, 0, 0);
    }
  }
#pragma unroll
  for (int nt = 0; nt < 8; ++nt) {
    const float bo = b_o[nt * 16 + nn];
#pragma unroll
    for (int r = 0; r < 4; ++r)
      out[(row0 + q * 4 + r) * VOCAB + nt * 16 + nn] = (float)acc[nt][r] * f + bo;
  }
}

extern "C" void kernel_launch(void* const* d_in, const int* in_sizes, int n_in,
                              void* d_out, int out_size, void* d_ws, size_t ws_size,
                              hipStream_t stream) {
  const int*   x    = (const int*)d_in[0];
  const float* emb  = (const float*)d_in[1];
  const float* W_ih = (const float*)d_in[2];
  const float* b_ih = (const float*)d_in[3];
  const float* W_hh = (const float*)d_in[4];
  const float* b_hh = (const float*)d_in[5];
  const float* W_ho = (const float*)d_in[6];
  const float* b_o  = (const float*)d_in[7];
  float* out = (float*)d_out;

  char* ws = (char*)d_ws;
  float*        E      = (float*)ws;                        // 256 KB (E', permuted cols)
  uint4*        Wf8    = (uint4*)(ws + (256 << 10));        // 320 KB (40 nt x 8 x 1 KB)
  float*        scf    = (float*)(ws + 589824);             // [0..1] scales
  float*        parts  = scf + 2;                           // [0..39] abs-max partials
  int8_t*       Hall   = (int8_t*)(ws + (1 << 20));         // 64 MB i8 (k-permuted cols)

  prep_kernel<<<56, 512, 0, stream>>>(emb, W_ih, b_ih, b_hh, W_hh, W_ho, E, parts);
  pack8_kernel<<<320, 64, 0, stream>>>(W_hh, W_ho, parts, scf, Wf8);
  rnn_kernel<<<16, 512, 0, stream>>>(x, E, Wf8, scf, Hall,
                                     out + (size_t)BATCH * SEQ * VOCAB);
  ygemm_kernel<<<(BATCH * SEQ) / 64, 256, 0, stream>>>(Hall, Wf8, scf, b_o, out);
}